// Round 4
// baseline (317.838 us; speedup 1.0000x reference)
//
#include <hip/hip_runtime.h>
#include <hip/hip_fp16.h>
#include <math.h>

// Problem constants
#define BB 256
#define LL 256
#define CC 128
#define HIDD 128
#define HH 4
#define DD 32
#define EE 4096
#define NN (BB*CC)          // 32768 nodes
#define LN_EPS 1e-5f

typedef short bf16x8 __attribute__((ext_vector_type(8)));
typedef _Float16 f16x8 __attribute__((ext_vector_type(8)));
typedef float f32x4 __attribute__((ext_vector_type(4)));

// ---------------------------------------------------------------------------
// helpers
// ---------------------------------------------------------------------------
__device__ __forceinline__ float red64(float p) {
    p += __shfl_xor(p, 32);
    p += __shfl_xor(p, 16);
    p += __shfl_xor(p, 8);
    p += __shfl_xor(p, 4);
    p += __shfl_xor(p, 2);
    p += __shfl_xor(p, 1);
    return p;
}
__device__ __forceinline__ unsigned bfr(float f) {        // fp32 -> bf16 bits, RNE
    unsigned x = __float_as_uint(f);
    return (x + 0x7FFFu + ((x >> 16) & 1u)) >> 16;
}
__device__ __forceinline__ unsigned pack2(float a, float b) { return bfr(a) | (bfr(b) << 16); }
__device__ __forceinline__ float b2f(unsigned u) { return __uint_as_float(u << 16); }

// ---------------------------------------------------------------------------
// MFMA GEMM building blocks. LDS tile: 128 rows x 16 chunks (chunk = 8 elems =
// 16B), physical chunk = c ^ (row&7)  -> frag reads are <=2-way conflicts.
// ---------------------------------------------------------------------------
__device__ __forceinline__ void stage_bf16_rm(ushort* lds, const ushort* src, int ldm, int t) {
    #pragma unroll
    for (int i = 0; i < 8; ++i) {
        int flat = i*256 + t;
        int r = flat >> 4, c = flat & 15;
        uint4 pk = *(const uint4*)(src + (size_t)r*ldm + c*8);
        *(uint4*)&lds[((r*16) + (c ^ (r & 7)))*8] = pk;
    }
}
// 128x128x128 tile: 4 waves, each 32 rows x 128 cols (2 m-frags x 8 n-frags)
__device__ __forceinline__ void mfma_tile_128(const ushort* Als, const ushort* Bls,
                                              f32x4 acc[2][8], int w, int lane) {
    int mr = lane & 15, quad = lane >> 4;
    #pragma unroll
    for (int ks = 0; ks < 4; ++ks) {
        int ca = ks*4 + quad;
        bf16x8 a[2], b[8];
        #pragma unroll
        for (int mf = 0; mf < 2; ++mf) {
            int m = w*32 + mf*16 + mr;
            a[mf] = *(const bf16x8*)&Als[((m*16) + (ca ^ (m & 7)))*8];
        }
        #pragma unroll
        for (int nf = 0; nf < 8; ++nf) {
            int n = nf*16 + mr;
            b[nf] = *(const bf16x8*)&Bls[((n*16) + (ca ^ (n & 7)))*8];
        }
        #pragma unroll
        for (int mf = 0; mf < 2; ++mf)
            #pragma unroll
            for (int nf = 0; nf < 8; ++nf)
                acc[mf][nf] = __builtin_amdgcn_mfma_f32_16x16x32_bf16(a[mf], b[nf], acc[mf][nf], 0, 0, 0);
    }
}
#define ZERO_ACC(acc) { _Pragma("unroll") for (int i_=0;i_<2;++i_) { _Pragma("unroll") for (int j_=0;j_<8;++j_) acc[i_][j_] = (f32x4){0.f,0.f,0.f,0.f}; } }

// ---------------------------------------------------------------------------
// K0: weight prep (blocks 0..63) + dense multiplicity table (block 64).
// mult[dst][src] = #edges(src,dst) (+1 on diagonal for self loops), fp16.
// Softmax identity: p = exp(l - m) * mult  (m = rowmax of BASE logits) gives
// exactly the segment softmax; mult==0 kills non-edges exactly.
// ---------------------------------------------------------------------------
__global__ __launch_bounds__(256) void prep_weights(const float* __restrict__ emb_W,
                                                    const float* __restrict__ lWl,
                                                    const float* __restrict__ lWr,
                                                    const float* __restrict__ pW,
                                                    const int* __restrict__ edge,
                                                    ushort* __restrict__ WembT,
                                                    ushort* __restrict__ WlrT,
                                                    ushort* __restrict__ WpT,
                                                    __half* __restrict__ mult_ds) {
    __shared__ int cnt[CC*CC];              // 64KB (used by block 64 only)
    int t = threadIdx.x;
    if (blockIdx.x == 64) {
        for (int i = t; i < CC*CC; i += 256) cnt[i] = 0;
        __syncthreads();
        for (int j = t; j < EE; j += 256) {
            int s = edge[j], d = edge[EE + j];
            atomicAdd(&cnt[s*CC + d], 1);
        }
        __syncthreads();
        for (int o = t; o < CC*CC; o += 256) {
            int dstc = o >> 7, srcc = o & 127;
            int c = cnt[srcc*CC + dstc] + ((srcc == dstc) ? 1 : 0);
            mult_ds[o] = __float2half((float)c);
        }
        return;
    }
    int gid = blockIdx.x * 256 + t;
    float v[8];
    if (gid < 4096) {                       // emb: 128 f x 32 l-chunks
        int f = gid >> 5, ch = gid & 31;
        #pragma unroll
        for (int j = 0; j < 8; ++j) v[j] = emb_W[(size_t)(ch*8 + j)*HIDD + f];
        uint4 pk; pk.x = pack2(v[0],v[1]); pk.y = pack2(v[2],v[3]);
        pk.z = pack2(v[4],v[5]); pk.w = pack2(v[6],v[7]);
        *(uint4*)&WembT[(size_t)f*LL + ch*8] = pk;
    } else if (gid < 12288) {               // lin: 4 mats x 128 f x 16 k-chunks
        int g = gid - 4096;
        int mat = g >> 11, f = (g >> 4) & 127, ch = g & 15;
        const float* src = ((mat & 1) ? lWr : lWl) + (size_t)(mat >> 1)*HIDD*HIDD;
        #pragma unroll
        for (int j = 0; j < 8; ++j) v[j] = src[(size_t)(ch*8 + j)*HIDD + f];
        uint4 pk; pk.x = pack2(v[0],v[1]); pk.y = pack2(v[2],v[3]);
        pk.z = pack2(v[4],v[5]); pk.w = pack2(v[6],v[7]);
        *(uint4*)&WlrT[(size_t)mat*HIDD*HIDD + (size_t)f*HIDD + ch*8] = pk;
    } else {                                // proj: 256 l x 16 k-chunks
        int g = gid - 12288;
        int l = g >> 4, ch = g & 15;
        #pragma unroll
        for (int j = 0; j < 8; ++j) v[j] = pW[(size_t)(ch*8 + j)*LL + l];
        uint4 pk; pk.x = pack2(v[0],v[1]); pk.y = pack2(v[2],v[3]);
        pk.z = pack2(v[4],v[5]); pk.w = pack2(v[6],v[7]);
        *(uint4*)&WpT[(size_t)l*HIDD + ch*8] = pk;
    }
}

// ---------------------------------------------------------------------------
// K2: embedding GEMM (MFMA), fused x-transpose. One block per b.
// Staging: coalesced float4 reads of x rows + packed b32 LDS transpose writes
// (rotated j to spread banks) — replaces the old 512B-stride scalar loads.
// ---------------------------------------------------------------------------
__global__ __launch_bounds__(256) void embed_mfma(const float* __restrict__ x,
                                                  const ushort* __restrict__ WembT,
                                                  const float* __restrict__ bias,
                                                  ushort* __restrict__ hout) {
    __shared__ __align__(16) ushort Als[128*16*8];
    __shared__ __align__(16) ushort Bls[128*16*8];
    int b = blockIdx.x;
    int t = threadIdx.x, lane = t & 63, w = t >> 6;
    f32x4 acc[2][8];
    ZERO_ACC(acc)
    #pragma unroll
    for (int kh = 0; kh < 2; ++kh) {
        if (kh) __syncthreads();
        const float4* x4 = (const float4*)(x + (size_t)b*LL*CC + (size_t)kh*128*CC);
        int rot = (t >> 3) & 3;
        #pragma unroll
        for (int i = 0; i < 8; ++i) {
            int flat = i*256 + t;               // 0..2047  (row-pairs x 32 f4)
            int lp = flat >> 5, c4 = flat & 31; // l = 2lp, 2lp+1
            float4 v0 = x4[(size_t)(2*lp)*32 + c4];
            float4 v1 = x4[(size_t)(2*lp + 1)*32 + c4];
            int lc = lp >> 2, lh = lp & 3;      // k-chunk, half-pair slot
            #pragma unroll
            for (int j0 = 0; j0 < 4; ++j0) {
                int j = (j0 + rot) & 3;
                int c = c4*4 + j;
                unsigned pk = pack2(((const float*)&v0)[j], ((const float*)&v1)[j]);
                *(unsigned*)&Als[((c*16) + (lc ^ (c & 7)))*8 + lh*2] = pk;
            }
        }
        stage_bf16_rm(Bls, WembT + kh*128, LL, t);
        __syncthreads();
        mfma_tile_128(Als, Bls, acc, w, lane);
    }
    int mr = lane & 15, quad = lane >> 4;
    #pragma unroll
    for (int nf = 0; nf < 8; ++nf) {
        int f = nf*16 + mr;
        float bv = bias[f];
        #pragma unroll
        for (int mf = 0; mf < 2; ++mf)
            #pragma unroll
            for (int r = 0; r < 4; ++r) {
                int node = w*32 + mf*16 + quad*4 + r;
                hout[((size_t)b*CC + node)*HIDD + f] = (ushort)bfr(acc[mf][nf][r] + bv);
            }
    }
}

// ---------------------------------------------------------------------------
// K3: xl+xr GEMMs fused (MFMA). Output fp16.
// ---------------------------------------------------------------------------
__global__ __launch_bounds__(256) void lin_mfma(const ushort* __restrict__ hmat,
                                                const ushort* __restrict__ WlT,
                                                const ushort* __restrict__ WrT,
                                                const float* __restrict__ bl,
                                                const float* __restrict__ br,
                                                __half* __restrict__ xlT,
                                                __half* __restrict__ xrT) {
    __shared__ __align__(16) ushort Als[128*16*8];
    __shared__ __align__(16) ushort Bls[128*16*8];
    int b = blockIdx.x;
    int t = threadIdx.x, lane = t & 63, w = t >> 6;
    int mr = lane & 15, quad = lane >> 4;
    stage_bf16_rm(Als, hmat + (size_t)b*CC*HIDD, HIDD, t);
    #pragma unroll
    for (int lr = 0; lr < 2; ++lr) {
        if (lr) __syncthreads();                     // Bls reuse guard
        stage_bf16_rm(Bls, lr ? WrT : WlT, HIDD, t);
        __syncthreads();
        f32x4 acc[2][8];
        ZERO_ACC(acc)
        mfma_tile_128(Als, Bls, acc, w, lane);
        const float* bias = lr ? br : bl;
        __half* out = lr ? xrT : xlT;
        #pragma unroll
        for (int nf = 0; nf < 8; ++nf) {
            int f = nf*16 + mr;
            float bv = bias[f];
            int h = f >> 5, d = f & 31;
            #pragma unroll
            for (int mf = 0; mf < 2; ++mf)
                #pragma unroll
                for (int r = 0; r < 4; ++r) {
                    int node = w*32 + mf*16 + quad*4 + r;
                    out[(((size_t)b*HH + h)*CC + node)*DD + d] = __float2half(acc[mf][nf][r] + bv);
                }
        }
    }
}

// ---------------------------------------------------------------------------
// K4: fused dense GATv2 attention. One block per (b,h), 256 threads =
// 4 src-groups (1/wave) x 64 lanes; each thread owns TWO dsts (dl, dl+64):
// xr rows pinned in regs -> each broadcast xl-row read feeds 96 half2 ops.
// Alpha is written straight to global Pg in MFMA-A-fragment layout
// (slot = mr*4 + (q^(mr&3))); PV A-frags are then coalesced 1KB L2-hot loads.
// LDS = 20.5KB -> 4 blocks/CU, grid exactly resident.
//   base l[dst][src] = 1.5*(Slq[src]+Srq[dst]) + 0.4*sum_k a_k|xl+xr|
//   p = exp(l - rowmax(base)) * mult;  alpha = p / sum p.
// ---------------------------------------------------------------------------
__global__ __launch_bounds__(256, 4) void gat_fused(const __half* __restrict__ xl_h,
                                                    const __half* __restrict__ xr_h,
                                                    const __half* __restrict__ mult_ds,
                                                    const float* __restrict__ att,
                                                    __half* __restrict__ xagg,
                                                    __half* __restrict__ Pg) {
    __shared__ __align__(16) __half xl_lds[CC*DD];     // 8KB  [src][feat]
    __shared__ __align__(16) __half xlT_swz[DD*16*8];  // 8KB  MFMA B (xor-swz)
    __shared__ float Slq[CC];                          // pre-scaled by 1.5
    __shared__ float rpart[4][CC];
    __shared__ float spart[4][CC];

    int bh = blockIdx.x;
    int h = bh & 3, b = bh >> 2;
    int t = threadIdx.x;
    int sg = t >> 6, dl = t & 63;          // wave = src-group; lane = dst-local
    int dstA = dl, dstB = dl + 64;

    // stage xl slice (coalesced)
    {
        const uint4* sp = (const uint4*)(xl_h + (size_t)bh * CC * DD);
        uint4* dp = (uint4*)xl_lds;
        dp[t] = sp[t];
        dp[t + 256] = sp[t + 256];
    }
    // qa2 = 0.4*att (fp16 pairs)
    __half2 qa2[16];
    const float* ag = att + h*DD;
    #pragma unroll
    for (int c = 0; c < 8; ++c) {
        float4 av = *(const float4*)&ag[c*4];
        qa2[2*c+0] = __floats2half2_rn(0.4f*av.x, 0.4f*av.y);
        qa2[2*c+1] = __floats2half2_rn(0.4f*av.z, 0.4f*av.w);
    }
    // xr rows for both dsts + Srq
    __half2 xrA[16], xrB[16];
    float fSA, fSB;
    {
        uint4 XA[4], XB[4];
        const uint4* pa = (const uint4*)(xr_h + ((size_t)bh*CC + dstA)*DD);
        const uint4* pb = (const uint4*)(xr_h + ((size_t)bh*CC + dstB)*DD);
        #pragma unroll
        for (int c = 0; c < 4; ++c) { XA[c] = pa[c]; XB[c] = pb[c]; }
        const __half2* va = (const __half2*)XA;
        const __half2* vb = (const __half2*)XB;
        float sA = 0.f, sB = 0.f;
        #pragma unroll
        for (int i = 0; i < 16; ++i) {
            xrA[i] = va[i]; xrB[i] = vb[i];
            __half2 p = __hmul2(qa2[i], xrA[i]);
            sA += __low2float(p) + __high2float(p);
            __half2 q = __hmul2(qa2[i], xrB[i]);
            sB += __low2float(q) + __high2float(q);
        }
        fSA = 1.5f * sA; fSB = 1.5f * sB;
    }
    __syncthreads();

    // Slq[n] = 1.5 * sum_k 0.4*a_k*xl[n,k]   (threads 0..127)
    if (t < CC) {
        uint4 R[4];
        const uint4* rp = (const uint4*)&xl_lds[t*DD];
        #pragma unroll
        for (int c = 0; c < 4; ++c) R[c] = rp[c];
        const __half2* rv = (const __half2*)R;
        __half2 s = __floats2half2_rn(0.f, 0.f);
        #pragma unroll
        for (int i = 0; i < 16; ++i) s = __hfma2(qa2[i], rv[i], s);
        Slq[t] = 1.5f * (__low2float(s) + __high2float(s));
    }
    // build transposed+swizzled xl for MFMA B operand
    for (int i = t; i < 512; i += 256) {
        int f = i >> 4, c = i & 15;
        __align__(16) __half v[8];
        #pragma unroll
        for (int e = 0; e < 8; ++e) v[e] = xl_lds[(c*8 + e)*DD + f];
        *(uint4*)&xlT_swz[((f*16) + (c ^ (f & 7)))*8] = *(uint4*)v;
    }
    __syncthreads();

    // ---- logits: 32 srcs x 2 dsts per thread, register-resident ----
    __half2 lvA[16], lvB[16];
    float pmA0 = -3.0e38f, pmA1 = pmA0, pmB0 = pmA0, pmB1 = pmA0;
    float lbufA = 0.f, lbufB = 0.f;
    #pragma unroll 4
    for (int j = 0; j < 32; ++j) {
        int src = sg*32 + j;
        uint4 R[4];
        const uint4* rp = (const uint4*)&xl_lds[src*DD];   // wave-uniform broadcast
        R[0] = rp[0]; R[1] = rp[1]; R[2] = rp[2]; R[3] = rp[3];
        float sl = Slq[src];
        const __half2* xv = (const __half2*)R;
        __half2 a0 = __floats2half2_rn(0.f,0.f), a1 = a0, a2 = a0, a3 = a0;
        __half2 b0 = a0, b1 = a0, b2 = a0, b3 = a0;
        #pragma unroll
        for (int q = 0; q < 4; ++q) {
            a0 = __hfma2(qa2[4*q+0], __habs2(__hadd2(xv[4*q+0], xrA[4*q+0])), a0);
            a1 = __hfma2(qa2[4*q+1], __habs2(__hadd2(xv[4*q+1], xrA[4*q+1])), a1);
            a2 = __hfma2(qa2[4*q+2], __habs2(__hadd2(xv[4*q+2], xrA[4*q+2])), a2);
            a3 = __hfma2(qa2[4*q+3], __habs2(__hadd2(xv[4*q+3], xrA[4*q+3])), a3);
            b0 = __hfma2(qa2[4*q+0], __habs2(__hadd2(xv[4*q+0], xrB[4*q+0])), b0);
            b1 = __hfma2(qa2[4*q+1], __habs2(__hadd2(xv[4*q+1], xrB[4*q+1])), b1);
            b2 = __hfma2(qa2[4*q+2], __habs2(__hadd2(xv[4*q+2], xrB[4*q+2])), b2);
            b3 = __hfma2(qa2[4*q+3], __habs2(__hadd2(xv[4*q+3], xrB[4*q+3])), b3);
        }
        __half2 tsA = __hadd2(__hadd2(a0, a1), __hadd2(a2, a3));
        __half2 tsB = __hadd2(__hadd2(b0, b1), __hadd2(b2, b3));
        float lA = (fSA + sl) + (__low2float(tsA) + __high2float(tsA));
        float lB = (fSB + sl) + (__low2float(tsB) + __high2float(tsB));
        if (j & 1) {
            pmA1 = fmaxf(pmA1, lA); pmB1 = fmaxf(pmB1, lB);
            lvA[j >> 1] = __floats2half2_rn(lbufA, lA);
            lvB[j >> 1] = __floats2half2_rn(lbufB, lB);
        } else {
            pmA0 = fmaxf(pmA0, lA); pmB0 = fmaxf(pmB0, lB);
            lbufA = lA; lbufB = lB;
        }
    }
    rpart[sg][dstA] = fmaxf(pmA0, pmA1);
    rpart[sg][dstB] = fmaxf(pmB0, pmB1);
    __syncthreads();
    float mA = fmaxf(fmaxf(rpart[0][dstA], rpart[1][dstA]),
                     fmaxf(rpart[2][dstA], rpart[3][dstA]));
    float mB = fmaxf(fmaxf(rpart[0][dstB], rpart[1][dstB]),
                     fmaxf(rpart[2][dstB], rpart[3][dstB]));

    // multiplicity rows (L2-hot 32KB table)
    uint4 MAr[4], MBr[4];
    {
        const uint4* ma = (const uint4*)(mult_ds + (size_t)dstA*CC + sg*32);
        const uint4* mb = (const uint4*)(mult_ds + (size_t)dstB*CC + sg*32);
        #pragma unroll
        for (int c = 0; c < 4; ++c) { MAr[c] = ma[c]; MBr[c] = mb[c]; }
    }
    const __half* multA = (const __half*)MAr;
    const __half* multB = (const __half*)MBr;

    float sA0 = 0.f, sA1 = 0.f, sB0 = 0.f, sB1 = 0.f;
    #pragma unroll
    for (int i = 0; i < 16; ++i) {
        float eA0 = __expf(__low2float(lvA[i]) - mA) * __half2float(multA[2*i]);
        float eA1 = __expf(__high2float(lvA[i]) - mA) * __half2float(multA[2*i+1]);
        float eB0 = __expf(__low2float(lvB[i]) - mB) * __half2float(multB[2*i]);
        float eB1 = __expf(__high2float(lvB[i]) - mB) * __half2float(multB[2*i+1]);
        if (i & 1) { sA1 += eA0 + eA1; sB1 += eB0 + eB1; }
        else       { sA0 += eA0 + eA1; sB0 += eB0 + eB1; }
        lvA[i] = __floats2half2_rn(eA0, eA1);
        lvB[i] = __floats2half2_rn(eB0, eB1);
    }
    spart[sg][dstA] = sA0 + sA1;
    spart[sg][dstB] = sB0 + sB1;
    __syncthreads();
    float isA = 1.f / (((spart[0][dstA] + spart[1][dstA]) +
                        (spart[2][dstA] + spart[3][dstA])) + 1e-16f);
    float isB = 1.f / (((spart[0][dstB] + spart[1][dstB]) +
                        (spart[2][dstB] + spart[3][dstB])) + 1e-16f);

    // ---- write normalized alpha to Pg in MFMA-A-frag layout ----
    size_t pbase = (size_t)bh * CC * CC;
    {
        int mr = dl & 15, dr0 = dl >> 4;
        __half* pA = Pg + pbase + (((size_t)(dr0*4 + sg))*64)*8;
        __half* pB = Pg + pbase + (((size_t)((dr0 + 4)*4 + sg))*64)*8;
        #pragma unroll
        for (int q = 0; q < 4; ++q) {
            int slot = mr*4 + (q ^ (mr & 3));
            __align__(16) __half ovA[8], ovB[8];
            #pragma unroll
            for (int i = 0; i < 4; ++i) {
                __half2 vA = lvA[q*4 + i], vB = lvB[q*4 + i];
                ovA[2*i+0] = __float2half(__low2float(vA) * isA);
                ovA[2*i+1] = __float2half(__high2float(vA) * isA);
                ovB[2*i+0] = __float2half(__low2float(vB) * isB);
                ovB[2*i+1] = __float2half(__high2float(vB) * isB);
            }
            *(uint4*)&pA[slot*8] = *(uint4*)ovA;
            *(uint4*)&pB[slot*8] = *(uint4*)ovB;
        }
    }
    __syncthreads();

    // ---- PV on MFMA: wave sg owns dsts sg*32..+31 (2 m-frags) ----
    int quad = dl >> 4, mr = dl & 15;
    const __half* pb = Pg + pbase;
    f16x8 afr[2][4];
    #pragma unroll
    for (int mf = 0; mf < 2; ++mf) {
        int dr0 = sg*2 + mf;
        #pragma unroll
        for (int ks = 0; ks < 4; ++ks)
            afr[mf][ks] = *(const f16x8*)&pb[(((size_t)(dr0*4 + ks))*64 +
                                             mr*4 + (quad ^ (mr & 3)))*8];
    }
    f32x4 acc[2][2];
    #pragma unroll
    for (int i = 0; i < 2; ++i)
        #pragma unroll
        for (int j = 0; j < 2; ++j) acc[i][j] = (f32x4){0.f,0.f,0.f,0.f};
    #pragma unroll
    for (int ks = 0; ks < 4; ++ks) {
        int ca = ks*4 + quad;
        f16x8 bfr2[2];
        #pragma unroll
        for (int nf = 0; nf < 2; ++nf) {
            int n = nf*16 + mr;
            bfr2[nf] = *(const f16x8*)&xlT_swz[((n*16) + (ca ^ (n & 7)))*8];
        }
        #pragma unroll
        for (int mf = 0; mf < 2; ++mf)
            #pragma unroll
            for (int nf = 0; nf < 2; ++nf)
                acc[mf][nf] = __builtin_amdgcn_mfma_f32_16x16x32_f16(afr[mf][ks], bfr2[nf], acc[mf][nf], 0, 0, 0);
    }
    #pragma unroll
    for (int mf = 0; mf < 2; ++mf)
        #pragma unroll
        for (int nf = 0; nf < 2; ++nf) {
            int f = nf*16 + mr;
            #pragma unroll
            for (int r = 0; r < 4; ++r) {
                int node = sg*32 + mf*16 + quad*4 + r;
                xagg[(((size_t)b*CC + node)*HH + h)*DD + f] = __float2half(acc[mf][nf][r]);
            }
        }
}

// ---------------------------------------------------------------------------
// K5: per-node epilogue (2 nodes/block): bias -> ELU -> residual -> LayerNorm
// in-place on bf16 h; (layer 1) attn row = 0.25 * sum_h alpha (frag layout).
// ---------------------------------------------------------------------------
__global__ __launch_bounds__(256) void gat_epilogue(const __half* __restrict__ xagg,
                                                    const float* __restrict__ gbias,
                                                    const float* __restrict__ ln_g,
                                                    const float* __restrict__ ln_b,
                                                    const __half* __restrict__ Pws,
                                                    ushort* __restrict__ hmat,
                                                    float* __restrict__ attn_out) {
    __shared__ float wred[4], wred2[4];
    int t = threadIdx.x;
    int nl = t >> 7, f = t & 127;
    int node = blockIdx.x*2 + nl;
    int b = node >> 7, dstc = node & 127;

    float o = __half2float(xagg[(size_t)node*HIDD + f]) + gbias[f];
    o = o > 0.f ? o : (__expf(o) - 1.f);
    float hv = b2f((unsigned)hmat[(size_t)node*HIDD + f]) + o;

    float sum = red64(hv);
    if ((t & 63) == 0) wred[t >> 6] = sum;
    __syncthreads();
    float mean = (wred[nl*2] + wred[nl*2+1]) * 0.0078125f;
    float d = hv - mean;
    float q = red64(d * d);
    if ((t & 63) == 0) wred2[t >> 6] = q;
    __syncthreads();
    float var = (wred2[nl*2] + wred2[nl*2+1]) * 0.0078125f;
    hmat[(size_t)node*HIDD + f] = (ushort)bfr(d * rsqrtf(var + LN_EPS) * ln_g[f] + ln_b[f]);

    if (attn_out) {
        // alpha[bh][dst=dstc][src=f] in MFMA-A frag layout
        int ks = f >> 5, qq = (f >> 3) & 3, e = f & 7;
        int mr = dstc & 15, dr0 = dstc >> 4;
        int slot = mr*4 + (qq ^ (mr & 3));
        size_t off = ((size_t)(dr0*4 + ks)*64 + slot)*8 + e;
        float a = 0.f;
        #pragma unroll
        for (int hh = 0; hh < HH; ++hh)
            a += __half2float(Pws[(size_t)(b*HH + hh)*CC*CC + off]);
        attn_out[(size_t)node*CC + f] = 0.25f * a;
    }
}

// ---------------------------------------------------------------------------
// K6: projection GEMM (MFMA) with fused output transpose.
// ---------------------------------------------------------------------------
__global__ __launch_bounds__(256) void proj_mfma(const ushort* __restrict__ hmat,
                                                 const ushort* __restrict__ WpT,
                                                 const float* __restrict__ bias,
                                                 float* __restrict__ out) {
    __shared__ __align__(16) ushort Als[128*16*8];
    __shared__ __align__(16) ushort Bls[128*16*8];
    int l0 = blockIdx.x * 128;
    int b  = blockIdx.y;
    int t = threadIdx.x, lane = t & 63, w = t >> 6;
    f32x4 acc[2][8];
    ZERO_ACC(acc)
    stage_bf16_rm(Als, WpT + (size_t)l0*HIDD, HIDD, t);
    stage_bf16_rm(Bls, hmat + (size_t)b*CC*HIDD, HIDD, t);
    __syncthreads();
    mfma_tile_128(Als, Bls, acc, w, lane);
    int mr = lane & 15, quad = lane >> 4;
    #pragma unroll
    for (int nf = 0; nf < 8; ++nf) {
        int c = nf*16 + mr;
        #pragma unroll
        for (int mf = 0; mf < 2; ++mf)
            #pragma unroll
            for (int r = 0; r < 4; ++r) {
                int l = l0 + w*32 + mf*16 + quad*4 + r;
                out[((size_t)b*LL + l)*CC + c] = acc[mf][nf][r] + bias[l];
            }
    }
}

// ---------------------------------------------------------------------------
extern "C" void kernel_launch(void* const* d_in, const int* in_sizes, int n_in,
                              void* d_out, int out_size, void* d_ws, size_t ws_size,
                              hipStream_t stream) {
    const float* x        = (const float*)d_in[0];
    const int*   edge     = (const int*)d_in[1];
    const float* emb_W    = (const float*)d_in[2];
    const float* emb_b    = (const float*)d_in[3];
    const float* lin_l_W  = (const float*)d_in[4];
    const float* lin_l_b  = (const float*)d_in[5];
    const float* lin_r_W  = (const float*)d_in[6];
    const float* lin_r_b  = (const float*)d_in[7];
    const float* att      = (const float*)d_in[8];
    const float* gat_bias = (const float*)d_in[9];
    const float* ln_g     = (const float*)d_in[10];
    const float* ln_b     = (const float*)d_in[11];
    const float* proj_W   = (const float*)d_in[12];
    const float* proj_b   = (const float*)d_in[13];

    // workspace: h(bf16) | xl(fp16) | xr(fp16) | xagg(fp16) | Pg(fp16) | mult | W
    ushort* h     = (ushort*)d_ws;
    __half* xl_h  = (__half*)(h + (size_t)NN * HIDD);
    __half* xr_h  = xl_h + (size_t)NN * HIDD;
    __half* xagg  = xr_h + (size_t)NN * HIDD;
    __half* Pg    = xagg + (size_t)NN * HIDD;
    __half* mult_ds = Pg + (size_t)BB * HH * CC * CC;
    ushort* WembT = (ushort*)(mult_ds + (size_t)CC * CC);
    ushort* WlrT  = WembT + (size_t)CC*LL;
    ushort* WpT   = WlrT + (size_t)4*HIDD*HIDD;

    float* out0 = (float*)d_out;                       // (B, L, C)
    float* attn = out0 + (size_t)BB * LL * CC;         // (B, C, C)

    prep_weights<<<65, 256, 0, stream>>>(emb_W, lin_l_W, lin_r_W, proj_W, edge,
                                         WembT, WlrT, WpT, mult_ds);
    embed_mfma<<<BB, 256, 0, stream>>>(x, WembT, emb_b, h);
    for (int layer = 0; layer < 2; ++layer) {
        lin_mfma<<<BB, 256, 0, stream>>>(h,
            WlrT + (size_t)(layer*2 + 0)*HIDD*HIDD,
            WlrT + (size_t)(layer*2 + 1)*HIDD*HIDD,
            lin_l_b + layer*HIDD, lin_r_b + layer*HIDD,
            xl_h, xr_h);
        gat_fused<<<BB*HH, 256, 0, stream>>>(xl_h, xr_h, mult_ds,
            att + layer*HIDD, xagg, Pg);
        gat_epilogue<<<NN/2, 256, 0, stream>>>(xagg,
            gat_bias + layer*HIDD, ln_g + layer*HIDD, ln_b + layer*HIDD,
            (layer == 1) ? Pg : nullptr, h, (layer == 1) ? attn : nullptr);
    }
    proj_mfma<<<dim3(2, BB), 256, 0, stream>>>(h, WpT, proj_b, out0);
}

// Round 5
// 307.052 us; speedup vs baseline: 1.0351x; 1.0351x over previous
//
#include <hip/hip_runtime.h>
#include <hip/hip_fp16.h>
#include <math.h>

// Problem constants
#define BB 256
#define LL 256
#define CC 128
#define HIDD 128
#define HH 4
#define DD 32
#define EE 4096
#define NN (BB*CC)          // 32768 nodes
#define LN_EPS 1e-5f

typedef short bf16x8 __attribute__((ext_vector_type(8)));
typedef _Float16 f16x8 __attribute__((ext_vector_type(8)));
typedef float f32x4 __attribute__((ext_vector_type(4)));

// ---------------------------------------------------------------------------
// helpers
// ---------------------------------------------------------------------------
__device__ __forceinline__ float red64(float p) {
    p += __shfl_xor(p, 32);
    p += __shfl_xor(p, 16);
    p += __shfl_xor(p, 8);
    p += __shfl_xor(p, 4);
    p += __shfl_xor(p, 2);
    p += __shfl_xor(p, 1);
    return p;
}
__device__ __forceinline__ unsigned bfr(float f) {        // fp32 -> bf16 bits, RNE
    unsigned x = __float_as_uint(f);
    return (x + 0x7FFFu + ((x >> 16) & 1u)) >> 16;
}
__device__ __forceinline__ unsigned pack2(float a, float b) { return bfr(a) | (bfr(b) << 16); }
__device__ __forceinline__ float b2f(unsigned u) { return __uint_as_float(u << 16); }

// ---------------------------------------------------------------------------
// MFMA GEMM building blocks. LDS tile: 128 rows x 16 chunks (chunk = 8 elems =
// 16B), physical chunk = c ^ (row&7)  -> frag reads are <=2-way conflicts.
// ---------------------------------------------------------------------------
__device__ __forceinline__ void stage_bf16_rm(ushort* lds, const ushort* src, int ldm, int t) {
    #pragma unroll
    for (int i = 0; i < 8; ++i) {
        int flat = i*256 + t;
        int r = flat >> 4, c = flat & 15;
        uint4 pk = *(const uint4*)(src + (size_t)r*ldm + c*8);
        *(uint4*)&lds[((r*16) + (c ^ (r & 7)))*8] = pk;
    }
}
// 128x128x128 tile: 4 waves, each 32 rows x 128 cols (2 m-frags x 8 n-frags)
__device__ __forceinline__ void mfma_tile_128(const ushort* Als, const ushort* Bls,
                                              f32x4 acc[2][8], int w, int lane) {
    int mr = lane & 15, quad = lane >> 4;
    #pragma unroll
    for (int ks = 0; ks < 4; ++ks) {
        int ca = ks*4 + quad;
        bf16x8 a[2], b[8];
        #pragma unroll
        for (int mf = 0; mf < 2; ++mf) {
            int m = w*32 + mf*16 + mr;
            a[mf] = *(const bf16x8*)&Als[((m*16) + (ca ^ (m & 7)))*8];
        }
        #pragma unroll
        for (int nf = 0; nf < 8; ++nf) {
            int n = nf*16 + mr;
            b[nf] = *(const bf16x8*)&Bls[((n*16) + (ca ^ (n & 7)))*8];
        }
        #pragma unroll
        for (int mf = 0; mf < 2; ++mf)
            #pragma unroll
            for (int nf = 0; nf < 8; ++nf)
                acc[mf][nf] = __builtin_amdgcn_mfma_f32_16x16x32_bf16(a[mf], b[nf], acc[mf][nf], 0, 0, 0);
    }
}
#define ZERO_ACC(acc) { _Pragma("unroll") for (int i_=0;i_<2;++i_) { _Pragma("unroll") for (int j_=0;j_<8;++j_) acc[i_][j_] = (f32x4){0.f,0.f,0.f,0.f}; } }

// ---------------------------------------------------------------------------
// K0: weight prep (blocks 0..63) + dense multiplicity table (block 64).
// mult[dst][src] = #edges(src,dst) (+1 on diagonal for self loops), fp16.
// Softmax identity: p = exp(l - m) * mult  (m = rowmax of BASE logits) gives
// exactly the segment softmax; mult==0 kills non-edges exactly.
// ---------------------------------------------------------------------------
__global__ __launch_bounds__(256) void prep_weights(const float* __restrict__ emb_W,
                                                    const float* __restrict__ lWl,
                                                    const float* __restrict__ lWr,
                                                    const float* __restrict__ pW,
                                                    const int* __restrict__ edge,
                                                    ushort* __restrict__ WembT,
                                                    ushort* __restrict__ WlrT,
                                                    ushort* __restrict__ WpT,
                                                    __half* __restrict__ mult_ds) {
    __shared__ int cnt[CC*CC];              // 64KB (used by block 64 only)
    int t = threadIdx.x;
    if (blockIdx.x == 64) {
        for (int i = t; i < CC*CC; i += 256) cnt[i] = 0;
        __syncthreads();
        for (int j = t; j < EE; j += 256) {
            int s = edge[j], d = edge[EE + j];
            atomicAdd(&cnt[s*CC + d], 1);
        }
        __syncthreads();
        for (int o = t; o < CC*CC; o += 256) {
            int dstc = o >> 7, srcc = o & 127;
            int c = cnt[srcc*CC + dstc] + ((srcc == dstc) ? 1 : 0);
            mult_ds[o] = __float2half((float)c);
        }
        return;
    }
    int gid = blockIdx.x * 256 + t;
    float v[8];
    if (gid < 4096) {                       // emb: 128 f x 32 l-chunks
        int f = gid >> 5, ch = gid & 31;
        #pragma unroll
        for (int j = 0; j < 8; ++j) v[j] = emb_W[(size_t)(ch*8 + j)*HIDD + f];
        uint4 pk; pk.x = pack2(v[0],v[1]); pk.y = pack2(v[2],v[3]);
        pk.z = pack2(v[4],v[5]); pk.w = pack2(v[6],v[7]);
        *(uint4*)&WembT[(size_t)f*LL + ch*8] = pk;
    } else if (gid < 12288) {               // lin: 4 mats x 128 f x 16 k-chunks
        int g = gid - 4096;
        int mat = g >> 11, f = (g >> 4) & 127, ch = g & 15;
        const float* src = ((mat & 1) ? lWr : lWl) + (size_t)(mat >> 1)*HIDD*HIDD;
        #pragma unroll
        for (int j = 0; j < 8; ++j) v[j] = src[(size_t)(ch*8 + j)*HIDD + f];
        uint4 pk; pk.x = pack2(v[0],v[1]); pk.y = pack2(v[2],v[3]);
        pk.z = pack2(v[4],v[5]); pk.w = pack2(v[6],v[7]);
        *(uint4*)&WlrT[(size_t)mat*HIDD*HIDD + (size_t)f*HIDD + ch*8] = pk;
    } else {                                // proj: 256 l x 16 k-chunks
        int g = gid - 12288;
        int l = g >> 4, ch = g & 15;
        #pragma unroll
        for (int j = 0; j < 8; ++j) v[j] = pW[(size_t)(ch*8 + j)*LL + l];
        uint4 pk; pk.x = pack2(v[0],v[1]); pk.y = pack2(v[2],v[3]);
        pk.z = pack2(v[4],v[5]); pk.w = pack2(v[6],v[7]);
        *(uint4*)&WpT[(size_t)l*HIDD + ch*8] = pk;
    }
}

// ---------------------------------------------------------------------------
// K2: embedding GEMM (MFMA), fused x-transpose. One block per b.
// ---------------------------------------------------------------------------
__global__ __launch_bounds__(256) void embed_mfma(const float* __restrict__ x,
                                                  const ushort* __restrict__ WembT,
                                                  const float* __restrict__ bias,
                                                  ushort* __restrict__ hout) {
    __shared__ __align__(16) ushort Als[128*16*8];
    __shared__ __align__(16) ushort Bls[128*16*8];
    int b = blockIdx.x;
    int t = threadIdx.x, lane = t & 63, w = t >> 6;
    f32x4 acc[2][8];
    ZERO_ACC(acc)
    #pragma unroll
    for (int kh = 0; kh < 2; ++kh) {
        if (kh) __syncthreads();
        const float4* x4 = (const float4*)(x + (size_t)b*LL*CC + (size_t)kh*128*CC);
        int rot = (t >> 3) & 3;
        #pragma unroll
        for (int i = 0; i < 8; ++i) {
            int flat = i*256 + t;               // 0..2047  (row-pairs x 32 f4)
            int lp = flat >> 5, c4 = flat & 31; // l = 2lp, 2lp+1
            float4 v0 = x4[(size_t)(2*lp)*32 + c4];
            float4 v1 = x4[(size_t)(2*lp + 1)*32 + c4];
            int lc = lp >> 2, lh = lp & 3;      // k-chunk, half-pair slot
            #pragma unroll
            for (int j0 = 0; j0 < 4; ++j0) {
                int j = (j0 + rot) & 3;
                int c = c4*4 + j;
                unsigned pk = pack2(((const float*)&v0)[j], ((const float*)&v1)[j]);
                *(unsigned*)&Als[((c*16) + (lc ^ (c & 7)))*8 + lh*2] = pk;
            }
        }
        stage_bf16_rm(Bls, WembT + kh*128, LL, t);
        __syncthreads();
        mfma_tile_128(Als, Bls, acc, w, lane);
    }
    int mr = lane & 15, quad = lane >> 4;
    #pragma unroll
    for (int nf = 0; nf < 8; ++nf) {
        int f = nf*16 + mr;
        float bv = bias[f];
        #pragma unroll
        for (int mf = 0; mf < 2; ++mf)
            #pragma unroll
            for (int r = 0; r < 4; ++r) {
                int node = w*32 + mf*16 + quad*4 + r;
                hout[((size_t)b*CC + node)*HIDD + f] = (ushort)bfr(acc[mf][nf][r] + bv);
            }
    }
}

// ---------------------------------------------------------------------------
// K3: xl+xr GEMMs fused (MFMA). Output fp16.
// ---------------------------------------------------------------------------
__global__ __launch_bounds__(256) void lin_mfma(const ushort* __restrict__ hmat,
                                                const ushort* __restrict__ WlT,
                                                const ushort* __restrict__ WrT,
                                                const float* __restrict__ bl,
                                                const float* __restrict__ br,
                                                __half* __restrict__ xlT,
                                                __half* __restrict__ xrT) {
    __shared__ __align__(16) ushort Als[128*16*8];
    __shared__ __align__(16) ushort Bls[128*16*8];
    int b = blockIdx.x;
    int t = threadIdx.x, lane = t & 63, w = t >> 6;
    int mr = lane & 15, quad = lane >> 4;
    stage_bf16_rm(Als, hmat + (size_t)b*CC*HIDD, HIDD, t);
    #pragma unroll
    for (int lr = 0; lr < 2; ++lr) {
        if (lr) __syncthreads();                     // Bls reuse guard
        stage_bf16_rm(Bls, lr ? WrT : WlT, HIDD, t);
        __syncthreads();
        f32x4 acc[2][8];
        ZERO_ACC(acc)
        mfma_tile_128(Als, Bls, acc, w, lane);
        const float* bias = lr ? br : bl;
        __half* out = lr ? xrT : xlT;
        #pragma unroll
        for (int nf = 0; nf < 8; ++nf) {
            int f = nf*16 + mr;
            float bv = bias[f];
            int h = f >> 5, d = f & 31;
            #pragma unroll
            for (int mf = 0; mf < 2; ++mf)
                #pragma unroll
                for (int r = 0; r < 4; ++r) {
                    int node = w*32 + mf*16 + quad*4 + r;
                    out[(((size_t)b*HH + h)*CC + node)*DD + d] = __float2half(acc[mf][nf][r] + bv);
                }
        }
    }
}

// ---------------------------------------------------------------------------
// K4: fused dense GATv2 attention. One block per (b,h), 256 threads =
// 4 src-groups (1/wave) x 64 lanes; each thread owns TWO dsts (dl, dl+64).
// Logit loop FULLY unrolled -> lvA/lvB statically indexed, register-resident
// (the R3 `#pragma unroll 4` variant spilled them to scratch: VGPR=48).
// Alpha written to global Pg in MFMA-A-frag layout; PV A-frags are coalesced
// 1KB L2-hot loads. LDS ~20.5KB, launch_bounds(256,4): grid exactly resident.
// ---------------------------------------------------------------------------
__global__ __launch_bounds__(256, 4) void gat_fused(const __half* __restrict__ xl_h,
                                                    const __half* __restrict__ xr_h,
                                                    const __half* __restrict__ mult_ds,
                                                    const float* __restrict__ att,
                                                    __half* __restrict__ xagg,
                                                    __half* __restrict__ Pg) {
    __shared__ __align__(16) __half xl_lds[CC*DD];     // 8KB  [src][feat]
    __shared__ __align__(16) __half xlT_swz[DD*16*8];  // 8KB  MFMA B (xor-swz)
    __shared__ float Slq[CC];                          // pre-scaled by 1.5
    __shared__ float rpart[4][CC];
    __shared__ float spart[4][CC];

    int bh = blockIdx.x;
    int h = bh & 3, b = bh >> 2;
    int t = threadIdx.x;
    int sg = t >> 6, dl = t & 63;          // wave = src-group; lane = dst-local
    int dstA = dl, dstB = dl + 64;

    // stage xl slice (coalesced)
    {
        const uint4* sp = (const uint4*)(xl_h + (size_t)bh * CC * DD);
        uint4* dp = (uint4*)xl_lds;
        dp[t] = sp[t];
        dp[t + 256] = sp[t + 256];
    }
    // qa2 = 0.4*att (fp16 pairs)
    __half2 qa2[16];
    const float* ag = att + h*DD;
    #pragma unroll
    for (int c = 0; c < 8; ++c) {
        float4 av = *(const float4*)&ag[c*4];
        qa2[2*c+0] = __floats2half2_rn(0.4f*av.x, 0.4f*av.y);
        qa2[2*c+1] = __floats2half2_rn(0.4f*av.z, 0.4f*av.w);
    }
    // xr rows for both dsts + Srq
    __half2 xrA[16], xrB[16];
    float fSA, fSB;
    {
        uint4 XA[4], XB[4];
        const uint4* pa = (const uint4*)(xr_h + ((size_t)bh*CC + dstA)*DD);
        const uint4* pb = (const uint4*)(xr_h + ((size_t)bh*CC + dstB)*DD);
        #pragma unroll
        for (int c = 0; c < 4; ++c) { XA[c] = pa[c]; XB[c] = pb[c]; }
        const __half2* va = (const __half2*)XA;
        const __half2* vb = (const __half2*)XB;
        float sA = 0.f, sB = 0.f;
        #pragma unroll
        for (int i = 0; i < 16; ++i) {
            xrA[i] = va[i]; xrB[i] = vb[i];
            __half2 p = __hmul2(qa2[i], xrA[i]);
            sA += __low2float(p) + __high2float(p);
            __half2 q = __hmul2(qa2[i], xrB[i]);
            sB += __low2float(q) + __high2float(q);
        }
        fSA = 1.5f * sA; fSB = 1.5f * sB;
    }
    __syncthreads();

    // Slq[n] = 1.5 * sum_k 0.4*a_k*xl[n,k]   (threads 0..127)
    if (t < CC) {
        uint4 R[4];
        const uint4* rp = (const uint4*)&xl_lds[t*DD];
        #pragma unroll
        for (int c = 0; c < 4; ++c) R[c] = rp[c];
        const __half2* rv = (const __half2*)R;
        __half2 s = __floats2half2_rn(0.f, 0.f);
        #pragma unroll
        for (int i = 0; i < 16; ++i) s = __hfma2(qa2[i], rv[i], s);
        Slq[t] = 1.5f * (__low2float(s) + __high2float(s));
    }
    // build transposed+swizzled xl for MFMA B operand (f-major indexing:
    // each 32-lane half reads 64B contiguous -> ~4-way instead of 16-way)
    for (int i = t; i < 512; i += 256) {
        int f = i & 31, c = i >> 5;
        __align__(16) __half v[8];
        #pragma unroll
        for (int e = 0; e < 8; ++e) v[e] = xl_lds[(c*8 + e)*DD + f];
        *(uint4*)&xlT_swz[((f*16) + (c ^ (f & 7)))*8] = *(uint4*)v;
    }
    __syncthreads();

    // ---- logits: 32 srcs x 2 dsts per thread, FULLY unrolled ----
    __half2 lvA[16], lvB[16];
    float pmA0 = -3.0e38f, pmA1 = pmA0, pmB0 = pmA0, pmB1 = pmA0;
    float lbufA = 0.f, lbufB = 0.f;
    #pragma unroll
    for (int j = 0; j < 32; ++j) {
        int src = sg*32 + j;
        uint4 R[4];
        const uint4* rp = (const uint4*)&xl_lds[src*DD];   // wave-uniform broadcast
        R[0] = rp[0]; R[1] = rp[1]; R[2] = rp[2]; R[3] = rp[3];
        float sl = Slq[src];
        const __half2* xv = (const __half2*)R;
        __half2 a0 = __floats2half2_rn(0.f,0.f), a1 = a0, a2 = a0, a3 = a0;
        __half2 b0 = a0, b1 = a0, b2 = a0, b3 = a0;
        #pragma unroll
        for (int q = 0; q < 4; ++q) {
            a0 = __hfma2(qa2[4*q+0], __habs2(__hadd2(xv[4*q+0], xrA[4*q+0])), a0);
            a1 = __hfma2(qa2[4*q+1], __habs2(__hadd2(xv[4*q+1], xrA[4*q+1])), a1);
            a2 = __hfma2(qa2[4*q+2], __habs2(__hadd2(xv[4*q+2], xrA[4*q+2])), a2);
            a3 = __hfma2(qa2[4*q+3], __habs2(__hadd2(xv[4*q+3], xrA[4*q+3])), a3);
            b0 = __hfma2(qa2[4*q+0], __habs2(__hadd2(xv[4*q+0], xrB[4*q+0])), b0);
            b1 = __hfma2(qa2[4*q+1], __habs2(__hadd2(xv[4*q+1], xrB[4*q+1])), b1);
            b2 = __hfma2(qa2[4*q+2], __habs2(__hadd2(xv[4*q+2], xrB[4*q+2])), b2);
            b3 = __hfma2(qa2[4*q+3], __habs2(__hadd2(xv[4*q+3], xrB[4*q+3])), b3);
        }
        __half2 tsA = __hadd2(__hadd2(a0, a1), __hadd2(a2, a3));
        __half2 tsB = __hadd2(__hadd2(b0, b1), __hadd2(b2, b3));
        float lA = (fSA + sl) + (__low2float(tsA) + __high2float(tsA));
        float lB = (fSB + sl) + (__low2float(tsB) + __high2float(tsB));
        if (j & 1) {
            pmA1 = fmaxf(pmA1, lA); pmB1 = fmaxf(pmB1, lB);
            lvA[j >> 1] = __floats2half2_rn(lbufA, lA);
            lvB[j >> 1] = __floats2half2_rn(lbufB, lB);
        } else {
            pmA0 = fmaxf(pmA0, lA); pmB0 = fmaxf(pmB0, lB);
            lbufA = lA; lbufB = lB;
        }
    }
    rpart[sg][dstA] = fmaxf(pmA0, pmA1);
    rpart[sg][dstB] = fmaxf(pmB0, pmB1);
    __syncthreads();
    float mA = fmaxf(fmaxf(rpart[0][dstA], rpart[1][dstA]),
                     fmaxf(rpart[2][dstA], rpart[3][dstA]));
    float mB = fmaxf(fmaxf(rpart[0][dstB], rpart[1][dstB]),
                     fmaxf(rpart[2][dstB], rpart[3][dstB]));

    // multiplicity rows (L2-hot 32KB table)
    uint4 MAr[4], MBr[4];
    {
        const uint4* ma = (const uint4*)(mult_ds + (size_t)dstA*CC + sg*32);
        const uint4* mb = (const uint4*)(mult_ds + (size_t)dstB*CC + sg*32);
        #pragma unroll
        for (int c = 0; c < 4; ++c) { MAr[c] = ma[c]; MBr[c] = mb[c]; }
    }
    const __half* multA = (const __half*)MAr;
    const __half* multB = (const __half*)MBr;

    float sA0 = 0.f, sA1 = 0.f, sB0 = 0.f, sB1 = 0.f;
    #pragma unroll
    for (int i = 0; i < 16; ++i) {
        float eA0 = __expf(__low2float(lvA[i]) - mA) * __half2float(multA[2*i]);
        float eA1 = __expf(__high2float(lvA[i]) - mA) * __half2float(multA[2*i+1]);
        float eB0 = __expf(__low2float(lvB[i]) - mB) * __half2float(multB[2*i]);
        float eB1 = __expf(__high2float(lvB[i]) - mB) * __half2float(multB[2*i+1]);
        if (i & 1) { sA1 += eA0 + eA1; sB1 += eB0 + eB1; }
        else       { sA0 += eA0 + eA1; sB0 += eB0 + eB1; }
        lvA[i] = __floats2half2_rn(eA0, eA1);
        lvB[i] = __floats2half2_rn(eB0, eB1);
    }
    spart[sg][dstA] = sA0 + sA1;
    spart[sg][dstB] = sB0 + sB1;
    __syncthreads();
    float isA = 1.f / (((spart[0][dstA] + spart[1][dstA]) +
                        (spart[2][dstA] + spart[3][dstA])) + 1e-16f);
    float isB = 1.f / (((spart[0][dstB] + spart[1][dstB]) +
                        (spart[2][dstB] + spart[3][dstB])) + 1e-16f);

    // ---- write normalized alpha to Pg in MFMA-A-frag layout ----
    size_t pbase = (size_t)bh * CC * CC;
    {
        int mr = dl & 15, dr0 = dl >> 4;
        __half* pA = Pg + pbase + (((size_t)(dr0*4 + sg))*64)*8;
        __half* pB = Pg + pbase + (((size_t)((dr0 + 4)*4 + sg))*64)*8;
        #pragma unroll
        for (int q = 0; q < 4; ++q) {
            int slot = mr*4 + (q ^ (mr & 3));
            __align__(16) __half ovA[8], ovB[8];
            #pragma unroll
            for (int i = 0; i < 4; ++i) {
                __half2 vA = lvA[q*4 + i], vB = lvB[q*4 + i];
                ovA[2*i+0] = __float2half(__low2float(vA) * isA);
                ovA[2*i+1] = __float2half(__high2float(vA) * isA);
                ovB[2*i+0] = __float2half(__low2float(vB) * isB);
                ovB[2*i+1] = __float2half(__high2float(vB) * isB);
            }
            *(uint4*)&pA[slot*8] = *(uint4*)ovA;
            *(uint4*)&pB[slot*8] = *(uint4*)ovB;
        }
    }
    __syncthreads();

    // ---- PV on MFMA: wave sg owns dsts sg*32..+31 (2 m-frags) ----
    int quad = dl >> 4, mr = dl & 15;
    const __half* pb = Pg + pbase;
    f16x8 afr[2][4];
    #pragma unroll
    for (int mf = 0; mf < 2; ++mf) {
        int dr0 = sg*2 + mf;
        #pragma unroll
        for (int ks = 0; ks < 4; ++ks)
            afr[mf][ks] = *(const f16x8*)&pb[(((size_t)(dr0*4 + ks))*64 +
                                             mr*4 + (quad ^ (mr & 3)))*8];
    }
    f32x4 acc[2][2];
    #pragma unroll
    for (int i = 0; i < 2; ++i)
        #pragma unroll
        for (int j = 0; j < 2; ++j) acc[i][j] = (f32x4){0.f,0.f,0.f,0.f};
    #pragma unroll
    for (int ks = 0; ks < 4; ++ks) {
        int ca = ks*4 + quad;
        f16x8 bfr2[2];
        #pragma unroll
        for (int nf = 0; nf < 2; ++nf) {
            int n = nf*16 + mr;
            bfr2[nf] = *(const f16x8*)&xlT_swz[((n*16) + (ca ^ (n & 7)))*8];
        }
        #pragma unroll
        for (int mf = 0; mf < 2; ++mf)
            #pragma unroll
            for (int nf = 0; nf < 2; ++nf)
                acc[mf][nf] = __builtin_amdgcn_mfma_f32_16x16x32_f16(afr[mf][ks], bfr2[nf], acc[mf][nf], 0, 0, 0);
    }
    #pragma unroll
    for (int mf = 0; mf < 2; ++mf)
        #pragma unroll
        for (int nf = 0; nf < 2; ++nf) {
            int f = nf*16 + mr;
            #pragma unroll
            for (int r = 0; r < 4; ++r) {
                int node = sg*32 + mf*16 + quad*4 + r;
                xagg[(((size_t)b*CC + node)*HH + h)*DD + f] = __float2half(acc[mf][nf][r]);
            }
        }
}

// ---------------------------------------------------------------------------
// K5: per-node epilogue (2 nodes/block): bias -> ELU -> residual -> LayerNorm
// in-place on bf16 h; (layer 1) attn row = 0.25 * sum_h alpha (frag layout).
// ---------------------------------------------------------------------------
__global__ __launch_bounds__(256) void gat_epilogue(const __half* __restrict__ xagg,
                                                    const float* __restrict__ gbias,
                                                    const float* __restrict__ ln_g,
                                                    const float* __restrict__ ln_b,
                                                    const __half* __restrict__ Pws,
                                                    ushort* __restrict__ hmat,
                                                    float* __restrict__ attn_out) {
    __shared__ float wred[4], wred2[4];
    int t = threadIdx.x;
    int nl = t >> 7, f = t & 127;
    int node = blockIdx.x*2 + nl;
    int b = node >> 7, dstc = node & 127;

    float o = __half2float(xagg[(size_t)node*HIDD + f]) + gbias[f];
    o = o > 0.f ? o : (__expf(o) - 1.f);
    float hv = b2f((unsigned)hmat[(size_t)node*HIDD + f]) + o;

    float sum = red64(hv);
    if ((t & 63) == 0) wred[t >> 6] = sum;
    __syncthreads();
    float mean = (wred[nl*2] + wred[nl*2+1]) * 0.0078125f;
    float d = hv - mean;
    float q = red64(d * d);
    if ((t & 63) == 0) wred2[t >> 6] = q;
    __syncthreads();
    float var = (wred2[nl*2] + wred2[nl*2+1]) * 0.0078125f;
    hmat[(size_t)node*HIDD + f] = (ushort)bfr(d * rsqrtf(var + LN_EPS) * ln_g[f] + ln_b[f]);

    if (attn_out) {
        // alpha[bh][dst=dstc][src=f] in MFMA-A frag layout
        int ks = f >> 5, qq = (f >> 3) & 3, e = f & 7;
        int mr = dstc & 15, dr0 = dstc >> 4;
        int slot = mr*4 + (qq ^ (mr & 3));
        size_t off = ((size_t)(dr0*4 + ks)*64 + slot)*8 + e;
        float a = 0.f;
        #pragma unroll
        for (int hh = 0; hh < HH; ++hh)
            a += __half2float(Pws[(size_t)(b*HH + hh)*CC*CC + off]);
        attn_out[(size_t)node*CC + f] = 0.25f * a;
    }
}

// ---------------------------------------------------------------------------
// K6: projection GEMM (MFMA) with fused output transpose.
// ---------------------------------------------------------------------------
__global__ __launch_bounds__(256) void proj_mfma(const ushort* __restrict__ hmat,
                                                 const ushort* __restrict__ WpT,
                                                 const float* __restrict__ bias,
                                                 float* __restrict__ out) {
    __shared__ __align__(16) ushort Als[128*16*8];
    __shared__ __align__(16) ushort Bls[128*16*8];
    int l0 = blockIdx.x * 128;
    int b  = blockIdx.y;
    int t = threadIdx.x, lane = t & 63, w = t >> 6;
    f32x4 acc[2][8];
    ZERO_ACC(acc)
    stage_bf16_rm(Als, WpT + (size_t)l0*HIDD, HIDD, t);
    stage_bf16_rm(Bls, hmat + (size_t)b*CC*HIDD, HIDD, t);
    __syncthreads();
    mfma_tile_128(Als, Bls, acc, w, lane);
    int mr = lane & 15, quad = lane >> 4;
    #pragma unroll
    for (int nf = 0; nf < 8; ++nf) {
        int c = nf*16 + mr;
        #pragma unroll
        for (int mf = 0; mf < 2; ++mf)
            #pragma unroll
            for (int r = 0; r < 4; ++r) {
                int l = l0 + w*32 + mf*16 + quad*4 + r;
                out[((size_t)b*LL + l)*CC + c] = acc[mf][nf][r] + bias[l];
            }
    }
}

// ---------------------------------------------------------------------------
extern "C" void kernel_launch(void* const* d_in, const int* in_sizes, int n_in,
                              void* d_out, int out_size, void* d_ws, size_t ws_size,
                              hipStream_t stream) {
    const float* x        = (const float*)d_in[0];
    const int*   edge     = (const int*)d_in[1];
    const float* emb_W    = (const float*)d_in[2];
    const float* emb_b    = (const float*)d_in[3];
    const float* lin_l_W  = (const float*)d_in[4];
    const float* lin_l_b  = (const float*)d_in[5];
    const float* lin_r_W  = (const float*)d_in[6];
    const float* lin_r_b  = (const float*)d_in[7];
    const float* att      = (const float*)d_in[8];
    const float* gat_bias = (const float*)d_in[9];
    const float* ln_g     = (const float*)d_in[10];
    const float* ln_b     = (const float*)d_in[11];
    const float* proj_W   = (const float*)d_in[12];
    const float* proj_b   = (const float*)d_in[13];

    // workspace: h(bf16) | xl(fp16) | xr(fp16) | xagg(fp16) | Pg(fp16) | mult | W
    ushort* h     = (ushort*)d_ws;
    __half* xl_h  = (__half*)(h + (size_t)NN * HIDD);
    __half* xr_h  = xl_h + (size_t)NN * HIDD;
    __half* xagg  = xr_h + (size_t)NN * HIDD;
    __half* Pg    = xagg + (size_t)NN * HIDD;
    __half* mult_ds = Pg + (size_t)BB * HH * CC * CC;
    ushort* WembT = (ushort*)(mult_ds + (size_t)CC * CC);
    ushort* WlrT  = WembT + (size_t)CC*LL;
    ushort* WpT   = WlrT + (size_t)4*HIDD*HIDD;

    float* out0 = (float*)d_out;                       // (B, L, C)
    float* attn = out0 + (size_t)BB * LL * CC;         // (B, C, C)

    prep_weights<<<65, 256, 0, stream>>>(emb_W, lin_l_W, lin_r_W, proj_W, edge,
                                         WembT, WlrT, WpT, mult_ds);
    embed_mfma<<<BB, 256, 0, stream>>>(x, WembT, emb_b, h);
    for (int layer = 0; layer < 2; ++layer) {
        lin_mfma<<<BB, 256, 0, stream>>>(h,
            WlrT + (size_t)(layer*2 + 0)*HIDD*HIDD,
            WlrT + (size_t)(layer*2 + 1)*HIDD*HIDD,
            lin_l_b + layer*HIDD, lin_r_b + layer*HIDD,
            xl_h, xr_h);
        gat_fused<<<BB*HH, 256, 0, stream>>>(xl_h, xr_h, mult_ds,
            att + layer*HIDD, xagg, Pg);
        gat_epilogue<<<NN/2, 256, 0, stream>>>(xagg,
            gat_bias + layer*HIDD, ln_g + layer*HIDD, ln_b + layer*HIDD,
            (layer == 1) ? Pg : nullptr, h, (layer == 1) ? attn : nullptr);
    }
    proj_mfma<<<dim3(2, BB), 256, 0, stream>>>(h, WpT, proj_b, out0);
}

// Round 6
// 288.269 us; speedup vs baseline: 1.1026x; 1.0652x over previous
//
#include <hip/hip_runtime.h>
#include <hip/hip_fp16.h>
#include <math.h>

// Problem constants
#define BB 256
#define LL 256
#define CC 128
#define HIDD 128
#define HH 4
#define DD 32
#define EE 4096
#define NN (BB*CC)          // 32768 nodes
#define LN_EPS 1e-5f

typedef short bf16x8 __attribute__((ext_vector_type(8)));
typedef _Float16 f16x8 __attribute__((ext_vector_type(8)));
typedef float f32x4 __attribute__((ext_vector_type(4)));

// ---------------------------------------------------------------------------
// helpers
// ---------------------------------------------------------------------------
__device__ __forceinline__ float red64(float p) {
    p += __shfl_xor(p, 32);
    p += __shfl_xor(p, 16);
    p += __shfl_xor(p, 8);
    p += __shfl_xor(p, 4);
    p += __shfl_xor(p, 2);
    p += __shfl_xor(p, 1);
    return p;
}
__device__ __forceinline__ unsigned bfr(float f) {        // fp32 -> bf16 bits, RNE
    unsigned x = __float_as_uint(f);
    return (x + 0x7FFFu + ((x >> 16) & 1u)) >> 16;
}
__device__ __forceinline__ unsigned pack2(float a, float b) { return bfr(a) | (bfr(b) << 16); }
__device__ __forceinline__ float b2f(unsigned u) { return __uint_as_float(u << 16); }

// ---------------------------------------------------------------------------
// MFMA GEMM building blocks. LDS tile: 128 rows x 16 chunks (chunk = 8 elems =
// 16B), physical chunk = c ^ (row&7)  -> frag reads are <=2-way conflicts.
// ---------------------------------------------------------------------------
__device__ __forceinline__ void stage_bf16_rm(ushort* lds, const ushort* src, int ldm, int t) {
    #pragma unroll
    for (int i = 0; i < 8; ++i) {
        int flat = i*256 + t;
        int r = flat >> 4, c = flat & 15;
        uint4 pk = *(const uint4*)(src + (size_t)r*ldm + c*8);
        *(uint4*)&lds[((r*16) + (c ^ (r & 7)))*8] = pk;
    }
}
// 128x128x128 tile: 4 waves, each 32 rows x 128 cols (2 m-frags x 8 n-frags)
__device__ __forceinline__ void mfma_tile_128(const ushort* Als, const ushort* Bls,
                                              f32x4 acc[2][8], int w, int lane) {
    int mr = lane & 15, quad = lane >> 4;
    #pragma unroll
    for (int ks = 0; ks < 4; ++ks) {
        int ca = ks*4 + quad;
        bf16x8 a[2], b[8];
        #pragma unroll
        for (int mf = 0; mf < 2; ++mf) {
            int m = w*32 + mf*16 + mr;
            a[mf] = *(const bf16x8*)&Als[((m*16) + (ca ^ (m & 7)))*8];
        }
        #pragma unroll
        for (int nf = 0; nf < 8; ++nf) {
            int n = nf*16 + mr;
            b[nf] = *(const bf16x8*)&Bls[((n*16) + (ca ^ (n & 7)))*8];
        }
        #pragma unroll
        for (int mf = 0; mf < 2; ++mf)
            #pragma unroll
            for (int nf = 0; nf < 8; ++nf)
                acc[mf][nf] = __builtin_amdgcn_mfma_f32_16x16x32_bf16(a[mf], b[nf], acc[mf][nf], 0, 0, 0);
    }
}
#define ZERO_ACC(acc) { _Pragma("unroll") for (int i_=0;i_<2;++i_) { _Pragma("unroll") for (int j_=0;j_<8;++j_) acc[i_][j_] = (f32x4){0.f,0.f,0.f,0.f}; } }

// ---------------------------------------------------------------------------
// K0: weight prep (blocks 0..63) + dense multiplicity table (block 64).
// mult[dst][src] = #edges(src,dst) (+1 on diagonal for self loops), fp16.
// Softmax identity: p = exp(l - m) * mult  (m = rowmax of BASE logits) gives
// exactly the segment softmax; mult==0 kills non-edges exactly.
// ---------------------------------------------------------------------------
__global__ __launch_bounds__(256) void prep_weights(const float* __restrict__ emb_W,
                                                    const float* __restrict__ lWl,
                                                    const float* __restrict__ lWr,
                                                    const float* __restrict__ pW,
                                                    const int* __restrict__ edge,
                                                    ushort* __restrict__ WembT,
                                                    ushort* __restrict__ WlrT,
                                                    ushort* __restrict__ WpT,
                                                    __half* __restrict__ mult_ds) {
    __shared__ int cnt[CC*CC];              // 64KB (used by block 64 only)
    int t = threadIdx.x;
    if (blockIdx.x == 64) {
        for (int i = t; i < CC*CC; i += 256) cnt[i] = 0;
        __syncthreads();
        for (int j = t; j < EE; j += 256) {
            int s = edge[j], d = edge[EE + j];
            atomicAdd(&cnt[s*CC + d], 1);
        }
        __syncthreads();
        for (int o = t; o < CC*CC; o += 256) {
            int dstc = o >> 7, srcc = o & 127;
            int c = cnt[srcc*CC + dstc] + ((srcc == dstc) ? 1 : 0);
            mult_ds[o] = __float2half((float)c);
        }
        return;
    }
    int gid = blockIdx.x * 256 + t;
    float v[8];
    if (gid < 4096) {                       // emb: 128 f x 32 l-chunks
        int f = gid >> 5, ch = gid & 31;
        #pragma unroll
        for (int j = 0; j < 8; ++j) v[j] = emb_W[(size_t)(ch*8 + j)*HIDD + f];
        uint4 pk; pk.x = pack2(v[0],v[1]); pk.y = pack2(v[2],v[3]);
        pk.z = pack2(v[4],v[5]); pk.w = pack2(v[6],v[7]);
        *(uint4*)&WembT[(size_t)f*LL + ch*8] = pk;
    } else if (gid < 12288) {               // lin: 4 mats x 128 f x 16 k-chunks
        int g = gid - 4096;
        int mat = g >> 11, f = (g >> 4) & 127, ch = g & 15;
        const float* src = ((mat & 1) ? lWr : lWl) + (size_t)(mat >> 1)*HIDD*HIDD;
        #pragma unroll
        for (int j = 0; j < 8; ++j) v[j] = src[(size_t)(ch*8 + j)*HIDD + f];
        uint4 pk; pk.x = pack2(v[0],v[1]); pk.y = pack2(v[2],v[3]);
        pk.z = pack2(v[4],v[5]); pk.w = pack2(v[6],v[7]);
        *(uint4*)&WlrT[(size_t)mat*HIDD*HIDD + (size_t)f*HIDD + ch*8] = pk;
    } else {                                // proj: 256 l x 16 k-chunks
        int g = gid - 12288;
        int l = g >> 4, ch = g & 15;
        #pragma unroll
        for (int j = 0; j < 8; ++j) v[j] = pW[(size_t)(ch*8 + j)*LL + l];
        uint4 pk; pk.x = pack2(v[0],v[1]); pk.y = pack2(v[2],v[3]);
        pk.z = pack2(v[4],v[5]); pk.w = pack2(v[6],v[7]);
        *(uint4*)&WpT[(size_t)l*HIDD + ch*8] = pk;
    }
}

// ---------------------------------------------------------------------------
// K2: embedding GEMM (MFMA), fused x-transpose. One block per b.
// ---------------------------------------------------------------------------
__global__ __launch_bounds__(256) void embed_mfma(const float* __restrict__ x,
                                                  const ushort* __restrict__ WembT,
                                                  const float* __restrict__ bias,
                                                  ushort* __restrict__ hout) {
    __shared__ __align__(16) ushort Als[128*16*8];
    __shared__ __align__(16) ushort Bls[128*16*8];
    int b = blockIdx.x;
    int t = threadIdx.x, lane = t & 63, w = t >> 6;
    f32x4 acc[2][8];
    ZERO_ACC(acc)
    #pragma unroll
    for (int kh = 0; kh < 2; ++kh) {
        if (kh) __syncthreads();
        const float4* x4 = (const float4*)(x + (size_t)b*LL*CC + (size_t)kh*128*CC);
        int rot = (t >> 3) & 3;
        #pragma unroll
        for (int i = 0; i < 8; ++i) {
            int flat = i*256 + t;               // 0..2047  (row-pairs x 32 f4)
            int lp = flat >> 5, c4 = flat & 31; // l = 2lp, 2lp+1
            float4 v0 = x4[(size_t)(2*lp)*32 + c4];
            float4 v1 = x4[(size_t)(2*lp + 1)*32 + c4];
            int lc = lp >> 2, lh = lp & 3;      // k-chunk, half-pair slot
            #pragma unroll
            for (int j0 = 0; j0 < 4; ++j0) {
                int j = (j0 + rot) & 3;
                int c = c4*4 + j;
                unsigned pk = pack2(((const float*)&v0)[j], ((const float*)&v1)[j]);
                *(unsigned*)&Als[((c*16) + (lc ^ (c & 7)))*8 + lh*2] = pk;
            }
        }
        stage_bf16_rm(Bls, WembT + kh*128, LL, t);
        __syncthreads();
        mfma_tile_128(Als, Bls, acc, w, lane);
    }
    int mr = lane & 15, quad = lane >> 4;
    #pragma unroll
    for (int nf = 0; nf < 8; ++nf) {
        int f = nf*16 + mr;
        float bv = bias[f];
        #pragma unroll
        for (int mf = 0; mf < 2; ++mf)
            #pragma unroll
            for (int r = 0; r < 4; ++r) {
                int node = w*32 + mf*16 + quad*4 + r;
                hout[((size_t)b*CC + node)*HIDD + f] = (ushort)bfr(acc[mf][nf][r] + bv);
            }
    }
}

// ---------------------------------------------------------------------------
// K3: xl+xr GEMMs fused (MFMA). Output fp16.
// ---------------------------------------------------------------------------
__global__ __launch_bounds__(256) void lin_mfma(const ushort* __restrict__ hmat,
                                                const ushort* __restrict__ WlT,
                                                const ushort* __restrict__ WrT,
                                                const float* __restrict__ bl,
                                                const float* __restrict__ br,
                                                __half* __restrict__ xlT,
                                                __half* __restrict__ xrT) {
    __shared__ __align__(16) ushort Als[128*16*8];
    __shared__ __align__(16) ushort Bls[128*16*8];
    int b = blockIdx.x;
    int t = threadIdx.x, lane = t & 63, w = t >> 6;
    int mr = lane & 15, quad = lane >> 4;
    stage_bf16_rm(Als, hmat + (size_t)b*CC*HIDD, HIDD, t);
    #pragma unroll
    for (int lr = 0; lr < 2; ++lr) {
        if (lr) __syncthreads();                     // Bls reuse guard
        stage_bf16_rm(Bls, lr ? WrT : WlT, HIDD, t);
        __syncthreads();
        f32x4 acc[2][8];
        ZERO_ACC(acc)
        mfma_tile_128(Als, Bls, acc, w, lane);
        const float* bias = lr ? br : bl;
        __half* out = lr ? xrT : xlT;
        #pragma unroll
        for (int nf = 0; nf < 8; ++nf) {
            int f = nf*16 + mr;
            float bv = bias[f];
            int h = f >> 5, d = f & 31;
            #pragma unroll
            for (int mf = 0; mf < 2; ++mf)
                #pragma unroll
                for (int r = 0; r < 4; ++r) {
                    int node = w*32 + mf*16 + quad*4 + r;
                    out[(((size_t)b*HH + h)*CC + node)*DD + d] = __float2half(acc[mf][nf][r] + bv);
                }
        }
    }
}

// ---------------------------------------------------------------------------
// K4: fused dense GATv2 attention. One block per (b,h), 256 threads =
// 4 src-groups (1/wave) x 64 lanes; each thread owns TWO dsts (dl, dl+64).
// P-frag lives in LDS via OVERLAY: after the softmax reductions, the
// xl/Slq/rpart/spart region (12.5KB of a 32KB buffer) is dead and the
// normalized alpha is written there in MFMA-A-frag layout. Layer 1 also
// streams row-major alpha to global for the epilogue/attention map.
// Total LDS 40KB -> 4 blocks/CU = the full 160KB pool, grid exactly resident.
// amdgpu_waves_per_eu(4,4): occupancy is LDS-capped at 4 waves/EU anyway, so
// let regalloc use the full 128 VGPRs (R5 squeezed to 64 -> spills).
// ---------------------------------------------------------------------------
#define SLOT(q, mr) ((mr)*4 + (((q) ^ (mr) ^ ((mr) >> 2)) & 3))

__global__ __launch_bounds__(256) __attribute__((amdgpu_waves_per_eu(4, 4)))
void gat_fused(const __half* __restrict__ xl_h,
               const __half* __restrict__ xr_h,
               const __half* __restrict__ mult_ds,
               const float* __restrict__ att,
               __half* __restrict__ xagg,
               __half* __restrict__ Pg) {
    __shared__ __align__(16) __half smemA[CC*CC];      // 32KB overlay region
    __shared__ __align__(16) __half xlT_swz[DD*16*8];  // 8KB  MFMA B (xor-swz)
    __half* xl_lds = smemA;                            // [src][feat] 8KB (phase 1)
    float*  Slq    = (float*)(smemA + CC*DD);          // 0.5KB (phase 1)
    float*  rp     = Slq + CC;                         // [4][CC] 2KB (phase 1)
    float*  sp     = rp + 4*CC;                        // [4][CC] 2KB (phase 1)
    __half* Pfrag  = smemA;                            // 32KB (phase 2)

    int bh = blockIdx.x;
    int h = bh & 3, b = bh >> 2;
    int t = threadIdx.x;
    int sg = t >> 6, dl = t & 63;          // wave = src-group; lane = dst-local
    int dstA = dl, dstB = dl + 64;

    // stage xl slice (coalesced)
    {
        const uint4* spg = (const uint4*)(xl_h + (size_t)bh * CC * DD);
        uint4* dp = (uint4*)xl_lds;
        dp[t] = spg[t];
        dp[t + 256] = spg[t + 256];
    }
    // qa2 = 0.4*att (fp16 pairs)
    __half2 qa2[16];
    const float* ag = att + h*DD;
    #pragma unroll
    for (int c = 0; c < 8; ++c) {
        float4 av = *(const float4*)&ag[c*4];
        qa2[2*c+0] = __floats2half2_rn(0.4f*av.x, 0.4f*av.y);
        qa2[2*c+1] = __floats2half2_rn(0.4f*av.z, 0.4f*av.w);
    }
    // xr rows for both dsts + Srq
    __half2 xrA[16], xrB[16];
    float fSA, fSB;
    {
        uint4 XA[4], XB[4];
        const uint4* pa = (const uint4*)(xr_h + ((size_t)bh*CC + dstA)*DD);
        const uint4* pb = (const uint4*)(xr_h + ((size_t)bh*CC + dstB)*DD);
        #pragma unroll
        for (int c = 0; c < 4; ++c) { XA[c] = pa[c]; XB[c] = pb[c]; }
        const __half2* va = (const __half2*)XA;
        const __half2* vb = (const __half2*)XB;
        float sA = 0.f, sB = 0.f;
        #pragma unroll
        for (int i = 0; i < 16; ++i) {
            xrA[i] = va[i]; xrB[i] = vb[i];
            __half2 p = __hmul2(qa2[i], xrA[i]);
            sA += __low2float(p) + __high2float(p);
            __half2 q = __hmul2(qa2[i], xrB[i]);
            sB += __low2float(q) + __high2float(q);
        }
        fSA = 1.5f * sA; fSB = 1.5f * sB;
    }
    __syncthreads();

    // Slq[n] = 1.5 * sum_k 0.4*a_k*xl[n,k]   (threads 0..127)
    if (t < CC) {
        uint4 R[4];
        const uint4* rpt = (const uint4*)&xl_lds[t*DD];
        #pragma unroll
        for (int c = 0; c < 4; ++c) R[c] = rpt[c];
        const __half2* rv = (const __half2*)R;
        __half2 s = __floats2half2_rn(0.f, 0.f);
        #pragma unroll
        for (int i = 0; i < 16; ++i) s = __hfma2(qa2[i], rv[i], s);
        Slq[t] = 1.5f * (__low2float(s) + __high2float(s));
    }
    // build transposed+swizzled xl for MFMA B operand
    for (int i = t; i < 512; i += 256) {
        int f = i & 31, c = i >> 5;
        __align__(16) __half v[8];
        #pragma unroll
        for (int e = 0; e < 8; ++e) v[e] = xl_lds[(c*8 + e)*DD + f];
        *(uint4*)&xlT_swz[((f*16) + (c ^ (f & 7)))*8] = *(uint4*)v;
    }
    __syncthreads();

    // ---- logits: 32 srcs x 2 dsts per thread, FULLY unrolled ----
    __half2 lvA[16], lvB[16];
    float pmA0 = -3.0e38f, pmA1 = pmA0, pmB0 = pmA0, pmB1 = pmA0;
    float lbufA = 0.f, lbufB = 0.f;
    #pragma unroll
    for (int j = 0; j < 32; ++j) {
        int src = sg*32 + j;
        uint4 R[4];
        const uint4* rpt = (const uint4*)&xl_lds[src*DD];  // wave-uniform broadcast
        R[0] = rpt[0]; R[1] = rpt[1]; R[2] = rpt[2]; R[3] = rpt[3];
        float sl = Slq[src];
        const __half2* xv = (const __half2*)R;
        __half2 a0 = __floats2half2_rn(0.f,0.f), a1 = a0, a2 = a0, a3 = a0;
        __half2 b0 = a0, b1 = a0, b2 = a0, b3 = a0;
        #pragma unroll
        for (int q = 0; q < 4; ++q) {
            a0 = __hfma2(qa2[4*q+0], __habs2(__hadd2(xv[4*q+0], xrA[4*q+0])), a0);
            a1 = __hfma2(qa2[4*q+1], __habs2(__hadd2(xv[4*q+1], xrA[4*q+1])), a1);
            a2 = __hfma2(qa2[4*q+2], __habs2(__hadd2(xv[4*q+2], xrA[4*q+2])), a2);
            a3 = __hfma2(qa2[4*q+3], __habs2(__hadd2(xv[4*q+3], xrA[4*q+3])), a3);
            b0 = __hfma2(qa2[4*q+0], __habs2(__hadd2(xv[4*q+0], xrB[4*q+0])), b0);
            b1 = __hfma2(qa2[4*q+1], __habs2(__hadd2(xv[4*q+1], xrB[4*q+1])), b1);
            b2 = __hfma2(qa2[4*q+2], __habs2(__hadd2(xv[4*q+2], xrB[4*q+2])), b2);
            b3 = __hfma2(qa2[4*q+3], __habs2(__hadd2(xv[4*q+3], xrB[4*q+3])), b3);
        }
        __half2 tsA = __hadd2(__hadd2(a0, a1), __hadd2(a2, a3));
        __half2 tsB = __hadd2(__hadd2(b0, b1), __hadd2(b2, b3));
        float lA = (fSA + sl) + (__low2float(tsA) + __high2float(tsA));
        float lB = (fSB + sl) + (__low2float(tsB) + __high2float(tsB));
        if (j & 1) {
            pmA1 = fmaxf(pmA1, lA); pmB1 = fmaxf(pmB1, lB);
            lvA[j >> 1] = __floats2half2_rn(lbufA, lA);
            lvB[j >> 1] = __floats2half2_rn(lbufB, lB);
        } else {
            pmA0 = fmaxf(pmA0, lA); pmB0 = fmaxf(pmB0, lB);
            lbufA = lA; lbufB = lB;
        }
    }
    rp[sg*CC + dstA] = fmaxf(pmA0, pmA1);
    rp[sg*CC + dstB] = fmaxf(pmB0, pmB1);
    __syncthreads();
    float mA = fmaxf(fmaxf(rp[0*CC + dstA], rp[1*CC + dstA]),
                     fmaxf(rp[2*CC + dstA], rp[3*CC + dstA]));
    float mB = fmaxf(fmaxf(rp[0*CC + dstB], rp[1*CC + dstB]),
                     fmaxf(rp[2*CC + dstB], rp[3*CC + dstB]));

    // multiplicity rows (L2-hot 32KB table)
    uint4 MAr[4], MBr[4];
    {
        const uint4* ma = (const uint4*)(mult_ds + (size_t)dstA*CC + sg*32);
        const uint4* mb = (const uint4*)(mult_ds + (size_t)dstB*CC + sg*32);
        #pragma unroll
        for (int c = 0; c < 4; ++c) { MAr[c] = ma[c]; MBr[c] = mb[c]; }
    }
    const __half* multA = (const __half*)MAr;
    const __half* multB = (const __half*)MBr;

    float sA0 = 0.f, sA1 = 0.f, sB0 = 0.f, sB1 = 0.f;
    #pragma unroll
    for (int i = 0; i < 16; ++i) {
        float eA0 = __expf(__low2float(lvA[i]) - mA) * __half2float(multA[2*i]);
        float eA1 = __expf(__high2float(lvA[i]) - mA) * __half2float(multA[2*i+1]);
        float eB0 = __expf(__low2float(lvB[i]) - mB) * __half2float(multB[2*i]);
        float eB1 = __expf(__high2float(lvB[i]) - mB) * __half2float(multB[2*i+1]);
        if (i & 1) { sA1 += eA0 + eA1; sB1 += eB0 + eB1; }
        else       { sA0 += eA0 + eA1; sB0 += eB0 + eB1; }
        lvA[i] = __floats2half2_rn(eA0, eA1);
        lvB[i] = __floats2half2_rn(eB0, eB1);
    }
    sp[sg*CC + dstA] = sA0 + sA1;
    sp[sg*CC + dstB] = sB0 + sB1;
    __syncthreads();
    float isA = 1.f / (((sp[0*CC + dstA] + sp[1*CC + dstA]) +
                        (sp[2*CC + dstA] + sp[3*CC + dstA])) + 1e-16f);
    float isB = 1.f / (((sp[0*CC + dstB] + sp[1*CC + dstB]) +
                        (sp[2*CC + dstB] + sp[3*CC + dstB])) + 1e-16f);
    __syncthreads();   // phase-1 region (xl/Slq/rp/sp) now dead -> overlay OK

    // ---- write normalized alpha: LDS P-frag (+ row-major global on layer 1) --
    {
        int mr = dl & 15, dr0 = dl >> 4;
        __half* pfA = &Pfrag[(((dr0    )*4 + sg)*64)*8];
        __half* pfB = &Pfrag[(((dr0 + 4)*4 + sg)*64)*8];
        __half* pgA = Pg ? Pg + (size_t)bh*CC*CC + (size_t)dstA*CC + sg*32 : nullptr;
        __half* pgB = Pg ? Pg + (size_t)bh*CC*CC + (size_t)dstB*CC + sg*32 : nullptr;
        #pragma unroll
        for (int q = 0; q < 4; ++q) {
            __align__(16) __half ovA[8], ovB[8];
            #pragma unroll
            for (int i = 0; i < 4; ++i) {
                __half2 vA = lvA[q*4 + i], vB = lvB[q*4 + i];
                ovA[2*i+0] = __float2half(__low2float(vA) * isA);
                ovA[2*i+1] = __float2half(__high2float(vA) * isA);
                ovB[2*i+0] = __float2half(__low2float(vB) * isB);
                ovB[2*i+1] = __float2half(__high2float(vB) * isB);
            }
            *(uint4*)&pfA[SLOT(q, mr)*8] = *(uint4*)ovA;
            *(uint4*)&pfB[SLOT(q, mr)*8] = *(uint4*)ovB;
            if (pgA) {
                *(uint4*)&pgA[q*8] = *(uint4*)ovA;
                *(uint4*)&pgB[q*8] = *(uint4*)ovB;
            }
        }
    }
    __syncthreads();

    // ---- PV on MFMA: wave sg owns dsts sg*32..+31 (2 m-frags) ----
    int quad = dl >> 4, mr = dl & 15;
    f16x8 afr[2][4];
    #pragma unroll
    for (int mf = 0; mf < 2; ++mf) {
        int dr0 = sg*2 + mf;
        #pragma unroll
        for (int ks = 0; ks < 4; ++ks)
            afr[mf][ks] = *(const f16x8*)&Pfrag[((dr0*4 + ks)*64 + SLOT(quad, mr))*8];
    }
    f32x4 acc[2][2];
    #pragma unroll
    for (int i = 0; i < 2; ++i)
        #pragma unroll
        for (int j = 0; j < 2; ++j) acc[i][j] = (f32x4){0.f,0.f,0.f,0.f};
    #pragma unroll
    for (int ks = 0; ks < 4; ++ks) {
        int ca = ks*4 + quad;
        f16x8 bfr2[2];
        #pragma unroll
        for (int nf = 0; nf < 2; ++nf) {
            int n = nf*16 + mr;
            bfr2[nf] = *(const f16x8*)&xlT_swz[((n*16) + (ca ^ (n & 7)))*8];
        }
        #pragma unroll
        for (int mf = 0; mf < 2; ++mf)
            #pragma unroll
            for (int nf = 0; nf < 2; ++nf)
                acc[mf][nf] = __builtin_amdgcn_mfma_f32_16x16x32_f16(afr[mf][ks], bfr2[nf], acc[mf][nf], 0, 0, 0);
    }
    #pragma unroll
    for (int mf = 0; mf < 2; ++mf)
        #pragma unroll
        for (int nf = 0; nf < 2; ++nf) {
            int f = nf*16 + mr;
            #pragma unroll
            for (int r = 0; r < 4; ++r) {
                int node = sg*32 + mf*16 + quad*4 + r;
                xagg[(((size_t)b*CC + node)*HH + h)*DD + f] = __float2half(acc[mf][nf][r]);
            }
        }
}

// ---------------------------------------------------------------------------
// K5: per-node epilogue, wave-per-node (4 nodes/block, no LDS, no barriers):
// bias -> ELU -> residual -> LayerNorm in-place on bf16 h; (layer 1)
// attn row = 0.25 * sum_h alpha, fully coalesced row-major reads.
// ---------------------------------------------------------------------------
__global__ __launch_bounds__(256) void gat_epilogue(const __half* __restrict__ xagg,
                                                    const float* __restrict__ gbias,
                                                    const float* __restrict__ ln_g,
                                                    const float* __restrict__ ln_b,
                                                    const __half* __restrict__ Pws,
                                                    ushort* __restrict__ hmat,
                                                    float* __restrict__ attn_out) {
    int t = threadIdx.x;
    int w = t >> 6, lane = t & 63;
    int node = blockIdx.x*4 + w;
    int b = node >> 7, dstc = node & 127;
    int f0 = lane*2;

    __half2 xa = *(const __half2*)&xagg[(size_t)node*HIDD + f0];
    unsigned hp = *(const unsigned*)&hmat[(size_t)node*HIDD + f0];
    float2 gb = *(const float2*)&gbias[f0];
    float o0 = __low2float(xa) + gb.x;
    float o1 = __high2float(xa) + gb.y;
    o0 = o0 > 0.f ? o0 : (__expf(o0) - 1.f);
    o1 = o1 > 0.f ? o1 : (__expf(o1) - 1.f);
    float hv0 = b2f(hp & 0xFFFFu) + o0;
    float hv1 = b2f(hp >> 16) + o1;

    float mean = red64(hv0 + hv1) * 0.0078125f;
    float d0 = hv0 - mean, d1 = hv1 - mean;
    float var = red64(d0*d0 + d1*d1) * 0.0078125f;
    float rs = rsqrtf(var + LN_EPS);
    float2 g2 = *(const float2*)&ln_g[f0];
    float2 be = *(const float2*)&ln_b[f0];
    *(unsigned*)&hmat[(size_t)node*HIDD + f0] =
        pack2(d0*rs*g2.x + be.x, d1*rs*g2.y + be.y);

    if (attn_out) {
        float a0 = 0.f, a1 = 0.f;
        #pragma unroll
        for (int hh = 0; hh < HH; ++hh) {
            __half2 v = *(const __half2*)&Pws[((size_t)(b*HH + hh)*CC + dstc)*CC + f0];
            a0 += __low2float(v);
            a1 += __high2float(v);
        }
        float2 o; o.x = 0.25f*a0; o.y = 0.25f*a1;
        *(float2*)&attn_out[(size_t)node*CC + f0] = o;
    }
}

// ---------------------------------------------------------------------------
// K6: projection GEMM (MFMA) with fused output transpose.
// ---------------------------------------------------------------------------
__global__ __launch_bounds__(256) void proj_mfma(const ushort* __restrict__ hmat,
                                                 const ushort* __restrict__ WpT,
                                                 const float* __restrict__ bias,
                                                 float* __restrict__ out) {
    __shared__ __align__(16) ushort Als[128*16*8];
    __shared__ __align__(16) ushort Bls[128*16*8];
    int l0 = blockIdx.x * 128;
    int b  = blockIdx.y;
    int t = threadIdx.x, lane = t & 63, w = t >> 6;
    f32x4 acc[2][8];
    ZERO_ACC(acc)
    stage_bf16_rm(Als, WpT + (size_t)l0*HIDD, HIDD, t);
    stage_bf16_rm(Bls, hmat + (size_t)b*CC*HIDD, HIDD, t);
    __syncthreads();
    mfma_tile_128(Als, Bls, acc, w, lane);
    int mr = lane & 15, quad = lane >> 4;
    #pragma unroll
    for (int nf = 0; nf < 8; ++nf) {
        int c = nf*16 + mr;
        #pragma unroll
        for (int mf = 0; mf < 2; ++mf)
            #pragma unroll
            for (int r = 0; r < 4; ++r) {
                int l = l0 + w*32 + mf*16 + quad*4 + r;
                out[((size_t)b*LL + l)*CC + c] = acc[mf][nf][r] + bias[l];
            }
    }
}

// ---------------------------------------------------------------------------
extern "C" void kernel_launch(void* const* d_in, const int* in_sizes, int n_in,
                              void* d_out, int out_size, void* d_ws, size_t ws_size,
                              hipStream_t stream) {
    const float* x        = (const float*)d_in[0];
    const int*   edge     = (const int*)d_in[1];
    const float* emb_W    = (const float*)d_in[2];
    const float* emb_b    = (const float*)d_in[3];
    const float* lin_l_W  = (const float*)d_in[4];
    const float* lin_l_b  = (const float*)d_in[5];
    const float* lin_r_W  = (const float*)d_in[6];
    const float* lin_r_b  = (const float*)d_in[7];
    const float* att      = (const float*)d_in[8];
    const float* gat_bias = (const float*)d_in[9];
    const float* ln_g     = (const float*)d_in[10];
    const float* ln_b     = (const float*)d_in[11];
    const float* proj_W   = (const float*)d_in[12];
    const float* proj_b   = (const float*)d_in[13];

    // workspace: h(bf16) | xl(fp16) | xr(fp16) | xagg(fp16) | Pg(fp16) | mult | W
    ushort* h     = (ushort*)d_ws;
    __half* xl_h  = (__half*)(h + (size_t)NN * HIDD);
    __half* xr_h  = xl_h + (size_t)NN * HIDD;
    __half* xagg  = xr_h + (size_t)NN * HIDD;
    __half* Pg    = xagg + (size_t)NN * HIDD;
    __half* mult_ds = Pg + (size_t)BB * HH * CC * CC;
    ushort* WembT = (ushort*)(mult_ds + (size_t)CC * CC);
    ushort* WlrT  = WembT + (size_t)CC*LL;
    ushort* WpT   = WlrT + (size_t)4*HIDD*HIDD;

    float* out0 = (float*)d_out;                       // (B, L, C)
    float* attn = out0 + (size_t)BB * LL * CC;         // (B, C, C)

    prep_weights<<<65, 256, 0, stream>>>(emb_W, lin_l_W, lin_r_W, proj_W, edge,
                                         WembT, WlrT, WpT, mult_ds);
    embed_mfma<<<BB, 256, 0, stream>>>(x, WembT, emb_b, h);
    for (int layer = 0; layer < 2; ++layer) {
        lin_mfma<<<BB, 256, 0, stream>>>(h,
            WlrT + (size_t)(layer*2 + 0)*HIDD*HIDD,
            WlrT + (size_t)(layer*2 + 1)*HIDD*HIDD,
            lin_l_b + layer*HIDD, lin_r_b + layer*HIDD,
            xl_h, xr_h);
        gat_fused<<<BB*HH, 256, 0, stream>>>(xl_h, xr_h, mult_ds,
            att + layer*HIDD, xagg, (layer == 1) ? Pg : nullptr);
        gat_epilogue<<<NN/4, 256, 0, stream>>>(xagg,
            gat_bias + layer*HIDD, ln_g + layer*HIDD, ln_b + layer*HIDD,
            (layer == 1) ? Pg : nullptr, h, (layer == 1) ? attn : nullptr);
    }
    proj_mfma<<<dim3(2, BB), 256, 0, stream>>>(h, WpT, proj_b, out0);
}